// Round 1
// 90.132 us; speedup vs baseline: 1.0128x; 1.0128x over previous
//
#include <hip/hip_runtime.h>
#include <math.h>

// KAN_layer: B=8192, IN_F=OUT_F=1024, GRID=5. idx_in == identity => x = X.
// spline is piecewise-linear with integer breakpoints in t = 2*clamp(x,-1,1)+2:
//   s(t) = c0 + sum_i (c[i+1]-c[i]) * clamp(t - i, 0, 1)   (exact for G=5)
//
// v2 changes vs v1 (theory: per-block param preamble was 32 uncoalesced
// scalar gathers ~= 1600 L1 line-transactions/wave, 12x the streaming phase):
//   - params staged via LDS with coalesced float4 copies (8 loads/thread)
//   - 1024 blocks x 8 rows (2x amortization; 4 blocks/CU, 128KB LDS resident)
//   - all 8 row loads issued before compute (single latency exposure)

#define B_ROWS   8192
#define N_FEAT   1024
#define N_BLOCKS 1024
#define ROWS_PER_BLOCK (B_ROWS / N_BLOCKS)   // 8

__global__ __launch_bounds__(256, 4) void kan_kernel(
    const float* __restrict__ X,
    const float* __restrict__ coeffs,   // (1024, 5) row-major
    const float* __restrict__ W,        // (1024, 2) row-major
    const float* __restrict__ bias,     // (1024,)
    float* __restrict__ Y)
{
    __shared__ float s_c[N_FEAT * 5];   // 20 KB
    __shared__ float s_w[N_FEAT * 2];   //  8 KB
    __shared__ float s_b[N_FEAT];       //  4 KB

    const int t = threadIdx.x;          // 0..255

    // ---- coalesced global->LDS staging of all per-column params ----
    {
        float4*       dc = reinterpret_cast<float4*>(s_c);
        const float4* gc = reinterpret_cast<const float4*>(coeffs);
#pragma unroll
        for (int u = 0; u < 5; ++u)     // 5120 floats = 1280 float4
            dc[u * 256 + t] = gc[u * 256 + t];

        float4*       dw = reinterpret_cast<float4*>(s_w);
        const float4* gw = reinterpret_cast<const float4*>(W);
#pragma unroll
        for (int u = 0; u < 2; ++u)     // 2048 floats = 512 float4
            dw[u * 256 + t] = gw[u * 256 + t];

        float4*       db = reinterpret_cast<float4*>(s_b);
        const float4* gb = reinterpret_cast<const float4*>(bias);
        db[t] = gb[t];                  // 1024 floats = 256 float4
    }
    __syncthreads();

    // ---- per-column params -> registers (one-time LDS reads) ----
    const int col0 = t * 4;             // this thread owns cols col0..col0+3
    float c0[4], d0[4], d1[4], d2[4], d3[4], w0[4], w1[4], bb[4];
#pragma unroll
    for (int j = 0; j < 4; ++j) {
        const int col = col0 + j;
        const float a0 = s_c[col * 5 + 0];
        const float a1 = s_c[col * 5 + 1];
        const float a2 = s_c[col * 5 + 2];
        const float a3 = s_c[col * 5 + 3];
        const float a4 = s_c[col * 5 + 4];
        c0[j] = a0;
        d0[j] = a1 - a0;
        d1[j] = a2 - a1;
        d2[j] = a3 - a2;
        d3[j] = a4 - a3;
        w0[j] = s_w[col * 2 + 0];
        w1[j] = s_w[col * 2 + 1];
        bb[j] = s_b[col];
    }

    // ---- 8 consecutive rows per block; loads batched up front ----
    const int row0 = blockIdx.x * ROWS_PER_BLOCK;

    float4 xs[ROWS_PER_BLOCK];
#pragma unroll
    for (int i = 0; i < ROWS_PER_BLOCK; ++i) {
        const size_t base = (size_t)(row0 + i) * N_FEAT + col0;
        xs[i] = *reinterpret_cast<const float4*>(X + base);
    }

#pragma unroll
    for (int i = 0; i < ROWS_PER_BLOCK; ++i) {
        const size_t base = (size_t)(row0 + i) * N_FEAT + col0;
        const float xv[4] = {xs[i].x, xs[i].y, xs[i].z, xs[i].w};
        float ys[4];

#pragma unroll
        for (int j = 0; j < 4; ++j) {
            const float x = xv[j];

            // silu(x) = x * sigmoid(x)
            const float sig  = 1.0f / (1.0f + __expf(-x));
            const float silu = x * sig;

            // b-spline linear via ramp sum (exact for G=5)
            const float xc = fminf(fmaxf(x, -1.0f), 1.0f);
            const float tt = fmaf(2.0f, xc, 2.0f);            // [0,4]
            const float r0 = fminf(tt, 1.0f);                  // tt >= 0 already
            const float r1 = fminf(fmaxf(tt - 1.0f, 0.0f), 1.0f);
            const float r2 = fminf(fmaxf(tt - 2.0f, 0.0f), 1.0f);
            const float r3 = fminf(fmaxf(tt - 3.0f, 0.0f), 1.0f);
            float s = c0[j];
            s = fmaf(d0[j], r0, s);
            s = fmaf(d1[j], r1, s);
            s = fmaf(d2[j], r2, s);
            s = fmaf(d3[j], r3, s);

            ys[j] = fmaf(silu, w0[j], fmaf(s, w1[j], bb[j]));
        }

        *reinterpret_cast<float4*>(Y + base) =
            make_float4(ys[0], ys[1], ys[2], ys[3]);
    }
}

extern "C" void kernel_launch(void* const* d_in, const int* in_sizes, int n_in,
                              void* d_out, int out_size, void* d_ws, size_t ws_size,
                              hipStream_t stream) {
    const float* X      = (const float*)d_in[0];   // (8192, 1024)
    const float* coeffs = (const float*)d_in[1];   // (1024, 5)
    const float* W      = (const float*)d_in[2];   // (1024, 2)
    const float* b      = (const float*)d_in[3];   // (1024,)
    float* Y            = (float*)d_out;           // (8192, 1024)

    kan_kernel<<<N_BLOCKS, 256, 0, stream>>>(X, coeffs, W, b, Y);
}